// Round 6
// baseline (1314.749 us; speedup 1.0000x reference)
//
#include <hip/hip_runtime.h>

// Q4_0 quantized linear: out[16, 11008] = x[16, 4096] @ ((w_q-8)*w_scale).T + bias
// All fp32; w_q holds int32 nibble values in [0,16).
//
// P1: lane=row GEMV, R=2 rows/thread (512 rows/block). Each block owns FOUR
//     32-k chunks spread 1024 apart (k = 32*j + 1024*i, i=0..3), accumulated
//     in registers -> only 32 split planes (22.5 MB partial) while the grid
//     is 22 x 32 = 704 blocks with 28 KB LDS -> 5 blocks/CU (20 waves), so
//     one block's staging burst overlaps four others' compute.
//     Code shape copied from the round-2/3 kernels that compiled clean
//     (VGPR 64, no scratch): byte-packed w in LDS with 9-word row stride
//     (gcd(9,32)=1 -> 2-way bank aliasing = free), xs[k][t] broadcast reads,
//     v_cvt_f32_ubyte dequant. Round 5's restructure spilled (~1.8 GB of
//     scratch traffic, 738 us) -- keep the allocator-friendly shape.
// P2: reduce 32 planes + bias -> out (round-4 proven, ~4 us). No atomics
//     (round 3: contended RMW write-through), no memset node needed.

constexpr int T       = 16;
constexpr int IN      = 4096;
constexpr int OUT     = 11008;
constexpr int NSCALE  = IN / 32;       // 128 scales per row
constexpr int THREADS = 256;
constexpr int R       = 2;             // rows per thread
constexpr int ROWSB   = THREADS * R;   // 512 rows per block
constexpr int NCH     = 4;             // spread 32-k chunks per block
constexpr int SPLITS  = 32;            // partial planes (= gridDim.y)
constexpr int WSTRIDE = 9;             // packed words per row (8 + 1 pad)
constexpr int XPAD    = 20;            // xs row stride floats (80 B, 16B-aligned)

// ---- P1: partial[j][t][row] = sum over chunks k in {32j+1024i} --------------
__global__ __launch_bounds__(THREADS, 4) void qlinear_p1(
    const int*   __restrict__ w_q,      // [OUT, IN]
    const float* __restrict__ w_scale,  // [OUT, NSCALE]
    const float* __restrict__ x,        // [T, IN]
    float*       __restrict__ partial)  // [SPLITS, T, OUT] (in ws)
{
    __shared__ __align__(16) float xs[NCH * 32][XPAD];      // 10 KiB
    __shared__ unsigned int        ws[ROWSB * WSTRIDE];     // 18 KiB

    const int tid  = threadIdx.x;
    const int row0 = blockIdx.x * ROWSB;   // 0..21 (last block ragged)
    const int j    = blockIdx.y;           // 0..31

    // ---- stage x for all 4 chunks: xs[i*32+k][t] = x[t][32j + 1024i + k] ----
    #pragma unroll
    for (int it = 0; it < NCH * 32 * T / THREADS; ++it) {  // 8
        int idx = it * THREADS + tid;
        int t   = idx >> 7;            // 0..15
        int kc  = idx & 127;           // i*32 + k
        int i   = kc >> 5;
        int k   = kc & 31;
        xs[kc][t] = x[t * IN + 32 * j + 1024 * i + k];
    }

    // ---- per-row scales, one per chunk (scalar loads, L2/L3-resident) ----
    float s[R][NCH], s8[R][NCH];
    #pragma unroll
    for (int r = 0; r < R; ++r) {
        int rg = min(row0 + tid + r * THREADS, OUT - 1);
        #pragma unroll
        for (int i = 0; i < NCH; ++i) {
            float sv = w_scale[(size_t)rg * NSCALE + j + 32 * i];
            s[r][i]  = sv;
            s8[r][i] = -8.0f * sv;     // exact
        }
    }

    float acc[R][T];
    #pragma unroll
    for (int r = 0; r < R; ++r)
        #pragma unroll
        for (int t = 0; t < T; ++t) acc[r][t] = 0.0f;

    for (int i = 0; i < NCH; ++i) {        // 4 chunk stages
        if (i) __syncthreads();            // ws overwrite hazard

        // stage w chunk: 512 rows x 32 ints -> packed bytes. flat int4 id f:
        // rr = f/8, b = f%8; 8 lanes cover one row's 128 contiguous bytes.
        #pragma unroll 8
        for (int it = 0; it < (ROWSB * 32 / 4) / THREADS; ++it) {  // 16
            int f  = it * THREADS + tid;
            int rr = f >> 3;
            int b  = f & 7;
            int rg = min(row0 + rr, OUT - 1);
            int4 v = *(const int4*)(w_q + (size_t)rg * IN + 32 * j + 1024 * i + b * 4);
            ws[rr * WSTRIDE + b] = (unsigned)v.x | ((unsigned)v.y << 8) |
                                   ((unsigned)v.z << 16) | ((unsigned)v.w << 24);
        }
        __syncthreads();   // staging -> compute (covers xs on first trip)

        for (int k4 = 0; k4 < 8; ++k4) {   // 4 k per packed word (rolled)
            unsigned q[R];
            #pragma unroll
            for (int r = 0; r < R; ++r)
                q[r] = ws[(tid + r * THREADS) * WSTRIDE + k4];  // 2-way = free

            #pragma unroll
            for (int kk = 0; kk < 4; ++kk) {
                const float4* xp = (const float4*)&xs[i * 32 + k4 * 4 + kk][0];
                float4 a = xp[0], b = xp[1], c = xp[2], d = xp[3];
                #pragma unroll
                for (int r = 0; r < R; ++r) {
                    // (q-8)*s single-rounded; extract -> v_cvt_f32_ubyte{kk}
                    float wv = fmaf((float)((q[r] >> (8 * kk)) & 0xffu),
                                    s[r][i], s8[r][i]);
                    acc[r][0]  = fmaf(wv, a.x, acc[r][0]);
                    acc[r][1]  = fmaf(wv, a.y, acc[r][1]);
                    acc[r][2]  = fmaf(wv, a.z, acc[r][2]);
                    acc[r][3]  = fmaf(wv, a.w, acc[r][3]);
                    acc[r][4]  = fmaf(wv, b.x, acc[r][4]);
                    acc[r][5]  = fmaf(wv, b.y, acc[r][5]);
                    acc[r][6]  = fmaf(wv, b.z, acc[r][6]);
                    acc[r][7]  = fmaf(wv, b.w, acc[r][7]);
                    acc[r][8]  = fmaf(wv, c.x, acc[r][8]);
                    acc[r][9]  = fmaf(wv, c.y, acc[r][9]);
                    acc[r][10] = fmaf(wv, c.z, acc[r][10]);
                    acc[r][11] = fmaf(wv, c.w, acc[r][11]);
                    acc[r][12] = fmaf(wv, d.x, acc[r][12]);
                    acc[r][13] = fmaf(wv, d.y, acc[r][13]);
                    acc[r][14] = fmaf(wv, d.z, acc[r][14]);
                    acc[r][15] = fmaf(wv, d.w, acc[r][15]);
                }
            }
        }
    }

    // ---- plain coalesced stores; each (j,t,row) owned by one thread ----
    #pragma unroll
    for (int r = 0; r < R; ++r) {
        int rg = row0 + tid + r * THREADS;
        if (rg < OUT) {
            #pragma unroll
            for (int t = 0; t < T; ++t)
                partial[((size_t)j * T + t) * OUT + rg] = acc[r][t];
        }
    }
}

// ---- P2: out[t][row] = sum_j partial[j][t][row] + bias[row] -----------------
__global__ __launch_bounds__(THREADS) void qreduce(
    const float* __restrict__ partial,
    const float* __restrict__ bias,
    float*       __restrict__ out)
{
    int row = blockIdx.x * THREADS + threadIdx.x;  // 43*256 = 11008 exact
    int t   = blockIdx.y;                          // 0..15
    float sum = bias[row];
    #pragma unroll 8
    for (int sb = 0; sb < SPLITS; ++sb)
        sum += partial[((size_t)sb * T + t) * OUT + row];
    out[(size_t)t * OUT + row] = sum;
}

extern "C" void kernel_launch(void* const* d_in, const int* in_sizes, int n_in,
                              void* d_out, int out_size, void* d_ws, size_t ws_size,
                              hipStream_t stream) {
    const float* x       = (const float*)d_in[0];
    const int*   w_q     = (const int*)d_in[1];
    const float* w_scale = (const float*)d_in[2];
    const float* bias    = (const float*)d_in[3];
    float*       out     = (float*)d_out;

    float* partial = (float*)d_ws;   // 32*16*11008 floats = 22.5 MB

    dim3 g1((OUT + ROWSB - 1) / ROWSB, SPLITS);   // 22 x 32 = 704 blocks
    qlinear_p1<<<g1, THREADS, 0, stream>>>(w_q, w_scale, x, partial);

    qreduce<<<dim3(OUT / THREADS, T), THREADS, 0, stream>>>(partial, bias, out);
}

// Round 7
// 580.363 us; speedup vs baseline: 2.2654x; 2.2654x over previous
//
#include <hip/hip_runtime.h>

// Q4_0 quantized linear: out[16, 11008] = x[16, 4096] @ ((w_q-8)*w_scale).T + bias
// All fp32; w_q holds int32 nibble values in [0,16).
//
// P1: lane=row GEMV, R=2 rows/thread (512 rows/block), CK=128 (4 scale
//     blocks), grid 22 x 32. x chunk staged in LDS as xs[k][t] -> inner-loop
//     x reads are same-address b128 broadcasts (free, deep pipe) -- fixes
//     round-4's global-x latency stall (VALUBusy 20%). w staged per 32-k
//     chunk, byte-packed, 9-word row stride (2-way bank alias = free both
//     directions; round-3-proven staging idiom).
//     SCRATCH-SPILL DISCIPLINE (rounds 5/6 lost ~2.9 GB to demoted locals):
//     the ONLY local arrays are acc0/acc1 with literal indices; scales are
//     16 individually named scalars; the 4 chunk bodies are macro-expanded
//     with literal chunk index -- no dynamically-indexed locals anywhere.
// P2: reduce 32 planes + bias -> out (round-4 proven). No atomics (round 3:
//     contended RMW write-through), no memset node needed.

constexpr int T       = 16;
constexpr int IN      = 4096;
constexpr int OUT     = 11008;
constexpr int NSCALE  = IN / 32;       // 128 scales per row
constexpr int THREADS = 256;
constexpr int ROWSB   = 512;           // rows per block (2 per thread)
constexpr int CK      = 128;           // k per block = 4 scale blocks
constexpr int SPLITS  = IN / CK;       // 32 partial planes
constexpr int WSTRIDE = 9;             // packed words per row (8 + 1 pad)
constexpr int XPAD    = 20;            // xs row stride floats (80 B, 16B-aligned)

#define PACK4(v) ((unsigned)(v).x | ((unsigned)(v).y << 8) | \
                  ((unsigned)(v).z << 16) | ((unsigned)(v).w << 24))

#define FMA16(A, WV, XA, XB, XC, XD)            \
    A[0]  = fmaf((WV), (XA).x, A[0]);           \
    A[1]  = fmaf((WV), (XA).y, A[1]);           \
    A[2]  = fmaf((WV), (XA).z, A[2]);           \
    A[3]  = fmaf((WV), (XA).w, A[3]);           \
    A[4]  = fmaf((WV), (XB).x, A[4]);           \
    A[5]  = fmaf((WV), (XB).y, A[5]);           \
    A[6]  = fmaf((WV), (XB).z, A[6]);           \
    A[7]  = fmaf((WV), (XB).w, A[7]);           \
    A[8]  = fmaf((WV), (XC).x, A[8]);           \
    A[9]  = fmaf((WV), (XC).y, A[9]);           \
    A[10] = fmaf((WV), (XC).z, A[10]);          \
    A[11] = fmaf((WV), (XC).w, A[11]);          \
    A[12] = fmaf((WV), (XD).x, A[12]);          \
    A[13] = fmaf((WV), (XD).y, A[13]);          \
    A[14] = fmaf((WV), (XD).z, A[14]);          \
    A[15] = fmaf((WV), (XD).w, A[15])

// One 32-k chunk: stage w (512 rows x 32 ints -> packed bytes), then
// dequant+FMA. I is a literal 0..3; SA/S8A/SB/S8B are named scalars.
#define CHUNK_BODY(I, SA, S8A, SB, S8B)                                       \
    {                                                                         \
        if ((I) != 0) __syncthreads();                                        \
        _Pragma("unroll 8")                                                   \
        for (int it = 0; it < 16; ++it) {                                     \
            int f  = it * THREADS + tid;                                      \
            int rr = f >> 3;                                                  \
            int bb = f & 7;                                                   \
            int rg = min(row0 + rr, OUT - 1);                                 \
            int4 v = *(const int4*)(w_q + (size_t)rg * IN + k0 + (I) * 32 +   \
                                    bb * 4);                                  \
            ws[rr * WSTRIDE + bb] = PACK4(v);                                 \
        }                                                                     \
        __syncthreads();                                                      \
        for (int k4 = 0; k4 < 8; ++k4) {                                      \
            unsigned q0 = ws[tid * WSTRIDE + k4];                             \
            unsigned q1 = ws[(tid + THREADS) * WSTRIDE + k4];                 \
            _Pragma("unroll")                                                 \
            for (int kk = 0; kk < 4; ++kk) {                                  \
                const float4* xp =                                            \
                    (const float4*)&xs[(I) * 32 + k4 * 4 + kk][0];            \
                float4 xa = xp[0], xb = xp[1], xc = xp[2], xd = xp[3];        \
                float wv0 = fmaf((float)((q0 >> (8 * kk)) & 0xffu),           \
                                 (SA), (S8A));                                \
                float wv1 = fmaf((float)((q1 >> (8 * kk)) & 0xffu),           \
                                 (SB), (S8B));                                \
                FMA16(acc0, wv0, xa, xb, xc, xd);                             \
                FMA16(acc1, wv1, xa, xb, xc, xd);                             \
            }                                                                 \
        }                                                                     \
    }

// ---- P1: partial[sb][t][row] = dot over this block's 128-k chunk ------------
__global__ __launch_bounds__(THREADS, 4) void qlinear_p1(
    const int*   __restrict__ w_q,      // [OUT, IN]
    const float* __restrict__ w_scale,  // [OUT, NSCALE]
    const float* __restrict__ x,        // [T, IN]
    float*       __restrict__ partial)  // [SPLITS, T, OUT] (in ws)
{
    __shared__ __align__(16) float xs[CK][XPAD];        // 10 KiB
    __shared__ unsigned int        ws[ROWSB * WSTRIDE]; // 18.4 KiB

    const int tid  = threadIdx.x;
    const int row0 = blockIdx.x * ROWSB;   // 0..21 (block 21 ragged)
    const int sb4  = blockIdx.y;           // 0..31
    const int k0   = sb4 * CK;

    // stage x chunk: xs[k][t] = x[t][k0+k]; global side coalesced over k.
    #pragma unroll
    for (int it = 0; it < CK * T / THREADS; ++it) {  // 8
        int idx = it * THREADS + tid;
        int t   = idx >> 7;
        int k   = idx & (CK - 1);
        xs[k][t] = x[t * IN + k0 + k];
    }

    // 4 scales per row for this 128-k chunk -> individually named scalars.
    const int r0 = min(row0 + tid, OUT - 1);
    const int r1 = min(row0 + tid + THREADS, OUT - 1);
    float4 scA = *(const float4*)(w_scale + (size_t)r0 * NSCALE + sb4 * 4);
    float4 scB = *(const float4*)(w_scale + (size_t)r1 * NSCALE + sb4 * 4);
    const float sA0 = scA.x, sA1 = scA.y, sA2 = scA.z, sA3 = scA.w;
    const float sB0 = scB.x, sB1 = scB.y, sB2 = scB.z, sB3 = scB.w;
    const float s8A0 = -8.0f * sA0, s8A1 = -8.0f * sA1;
    const float s8A2 = -8.0f * sA2, s8A3 = -8.0f * sA3;
    const float s8B0 = -8.0f * sB0, s8B1 = -8.0f * sB1;
    const float s8B2 = -8.0f * sB2, s8B3 = -8.0f * sB3;

    float acc0[T];
    float acc1[T];
    #pragma unroll
    for (int t = 0; t < T; ++t) { acc0[t] = 0.0f; acc1[t] = 0.0f; }

    CHUNK_BODY(0, sA0, s8A0, sB0, s8B0);
    CHUNK_BODY(1, sA1, s8A1, sB1, s8B1);
    CHUNK_BODY(2, sA2, s8A2, sB2, s8B2);
    CHUNK_BODY(3, sA3, s8A3, sB3, s8B3);

    // plain coalesced stores; each (sb,t,row) owned by exactly one thread
    const int rg0 = row0 + tid;
    const int rg1 = row0 + tid + THREADS;
    if (rg0 < OUT) {
        #pragma unroll
        for (int t = 0; t < T; ++t)
            partial[((size_t)sb4 * T + t) * OUT + rg0] = acc0[t];
    }
    if (rg1 < OUT) {
        #pragma unroll
        for (int t = 0; t < T; ++t)
            partial[((size_t)sb4 * T + t) * OUT + rg1] = acc1[t];
    }
}

// ---- P2: out[t][row] = sum_sb partial[sb][t][row] + bias[row] ---------------
__global__ __launch_bounds__(THREADS) void qreduce(
    const float* __restrict__ partial,
    const float* __restrict__ bias,
    float*       __restrict__ out)
{
    int row = blockIdx.x * THREADS + threadIdx.x;  // 43*256 = 11008 exact
    int t   = blockIdx.y;                          // 0..15
    float sum = bias[row];
    #pragma unroll 8
    for (int sb = 0; sb < SPLITS; ++sb)
        sum += partial[((size_t)sb * T + t) * OUT + row];
    out[(size_t)t * OUT + row] = sum;
}

extern "C" void kernel_launch(void* const* d_in, const int* in_sizes, int n_in,
                              void* d_out, int out_size, void* d_ws, size_t ws_size,
                              hipStream_t stream) {
    const float* x       = (const float*)d_in[0];
    const int*   w_q     = (const int*)d_in[1];
    const float* w_scale = (const float*)d_in[2];
    const float* bias    = (const float*)d_in[3];
    float*       out     = (float*)d_out;

    float* partial = (float*)d_ws;   // 32*16*11008 floats = 22.5 MB

    dim3 g1((OUT + ROWSB - 1) / ROWSB, SPLITS);   // 22 x 32 = 704 blocks
    qlinear_p1<<<g1, THREADS, 0, stream>>>(w_q, w_scale, x, partial);

    qreduce<<<dim3(OUT / THREADS, T), THREADS, 0, stream>>>(partial, bias, out);
}